// Round 10
// baseline (99.744 us; speedup 1.0000x reference)
//
#include <hip/hip_runtime.h>

// Problem constants
#define MD 4
#define PATCH 9          // 2*MD+1
#define NBAND 256        // band-compute blocks: (b, ty) = 4 * 64
#define NZERO 1024       // zero-streaming blocks
#define BT 1024          // threads per block (16 waves)
// feat1/feat2: (4, 256, 64, 64) fp32
// out: (4, 4096, 64, 64) fp32 = 256 MB
//
// out[b, ty*64+tx, y, x] = sum_c f1[b,c,y,x] * f2[b,c,ty,tx]  if |ty-y|<=4 && |tx-x|<=4, else 0.
//
// Fused kernel, row-disjoint partition:
//   zero blocks: rows |y-ty|>4 (~220 MB predicated float4 stream)
//   band blocks: rows |y-ty|<=4 (~36 MB computed)
// Band block: stage ALL of f2[b,:,ty,:] into padded 72-wide LDS rows (margins = 0), ONE
// barrier, then 16 waves (cq = channel quarter, dyg = dy triple) each do 64 channels x
// 3 dy rows: batched f1 global loads + 9 consecutive ds_reads (no load->shuffle chain).
// KEY vs R9: sF2 and sVals UNIONED in one 73.7 KB buffer -> 2 blocks/CU co-residency
// (R9's 94.4 KB forced 1 block/CU, serializing band after zero). All waves run a uniform
// 3-row shape so the barrier sequence is uniform; duplicate rows discarded at merge.

__global__ __launch_bounds__(BT, 8) void cv_kernel(
    const float* __restrict__ f1,
    const float* __restrict__ f2,
    float* __restrict__ out)
{
    const int tid = threadIdx.x;

    // ---------------- zero-streaming blocks ----------------
    if (blockIdx.x >= NBAND) {
        // float4 index i: bits [0:4)=x4, [4:10)=y, [10:16)=tx, [16:22)=ty, [22:24)=b
        float4* o4 = (float4*)out;
        const float4 z4 = make_float4(0.f, 0.f, 0.f, 0.f);
        const int total4 = 4 * 4096 * 64 * 16;            // 16,777,216
        const int stride = NZERO * BT;
        for (int i = (blockIdx.x - NBAND) * BT + tid; i < total4; i += stride) {
            int y  = (i >> 4) & 63;
            int ty = (i >> 16) & 63;
            int dy = y - ty;
            if (dy < -MD || dy > MD)
                o4[i] = z4;
        }
        return;
    }

    // ---------------- band-compute blocks ----------------
    const int bty = blockIdx.x;       // 0..255
    const int b   = bty >> 6;
    const int ty  = bty & 63;
    const int lane = tid & 63;        // u = x position
    const int w    = tid >> 6;        // 0..15
    const int cq   = w >> 2;          // channel quarter
    const int dyg  = w & 3;           // dy triple base: rows 2*dyg .. 2*dyg+2

    __shared__ float uLds[256 * 72];  // 73,728 B: sF2[256][72] during compute, sVals[64][81] after
    float (*sF2)[72] = (float(*)[72])uLds;

    // stage f2[b, c, ty, :] -> sF2[c][4..68), margins zeroed
    const float4* f2g = (const float4*)f2 + (size_t)(b * 256) * 1024 + ty * 16;
#pragma unroll
    for (int k = 0; k < 4; ++k) {
        int idx = k * BT + tid;       // 0..4095
        int cl = idx >> 4, x4 = idx & 15;
        *(float4*)&sF2[cl][4 + 4 * x4] = f2g[(size_t)cl * 1024 + x4];   // 16B-aligned
    }
    if (tid < 512) {
        int cl = tid >> 1, off = (tid & 1) ? 68 : 0;
        *(float4*)&sF2[cl][off] = make_float4(0.f, 0.f, 0.f, 0.f);
    }
    __syncthreads();

    // Uniform 3-row compute: rows dy0..dy0+2 (waves dyg<3 duplicate one row; discarded at merge)
    const int dy0 = dyg * 2;
    const int nd  = (dyg == 3) ? 3 : 2;

    float acc[3][PATCH];
#pragma unroll
    for (int i = 0; i < 3; ++i)
#pragma unroll
        for (int j = 0; j < PATCH; ++j) acc[i][j] = 0.f;

    int yoff[3];                      // clamped; invalid rows discarded at merge
#pragma unroll
    for (int i = 0; i < 3; ++i) {
        int y = ty + dy0 + i - MD;
        y = y < 0 ? 0 : (y > 63 ? 63 : y);
        yoff[i] = y * 64;
    }

    const float* f1b = f1 + (size_t)(b * 256 + cq * 64) * 4096 + lane;
    const float (*sF2w)[72] = &sF2[cq * 64];

#pragma unroll 4
    for (int c = 0; c < 64; ++c) {
        const float* f1c = f1b + (size_t)c * 4096;
        float f1v[3];
#pragma unroll
        for (int i = 0; i < 3; ++i)
            f1v[i] = f1c[yoff[i]];                    // batched coalesced global loads
        const float* wp = &sF2w[c][lane];
        float sh[PATCH];
#pragma unroll
        for (int dxi = 0; dxi < PATCH; ++dxi)
            sh[dxi] = wp[8 - dxi];                    // f2[c,ty,lane-dxi+4]; margins give 0
#pragma unroll
        for (int i = 0; i < 3; ++i)
#pragma unroll
            for (int dxi = 0; dxi < PATCH; ++dxi)
                acc[i][dxi] = fmaf(f1v[i], sh[dxi], acc[i][dxi]);
    }

    __syncthreads();                  // all sF2 reads complete; uLds becomes sVals
    float (*sVals)[81] = (float(*)[81])uLds;   // sVals[tx][dyi*9+dxi]
    for (int i = tid; i < 64 * 81; i += BT)
        (&sVals[0][0])[i] = 0.0f;
    __syncthreads();

    // Merge the 4 channel-quarter partials per entry; skip duplicate/invalid rows.
#pragma unroll
    for (int i = 0; i < 3; ++i) {
        if (i >= nd) continue;        // wave-uniform
        int dyi = dy0 + i;
        int y = ty + dyi - MD;
        if ((unsigned)y >= 64u) continue;
#pragma unroll
        for (int dxi = 0; dxi < PATCH; ++dxi) {
            int tx = lane - (dxi - MD);
            if ((unsigned)tx < 64u)
                atomicAdd(&sVals[tx][dyi * PATCH + dxi], acc[i][dxi]);  // stride 81: conflict-free
        }
    }

    __syncthreads();

    // Band rows: full 64-float rows (9-wide value window, zeros elsewhere).
    float4* out4 = (float4*)(out + (size_t)(b * 4096 + ty * 64) * 4096);
    const int q4 = tid & 15;          // float4 index within a row
    const int ro = tid >> 4;          // 0..63
    for (int rb = 0; rb < 64 * PATCH; rb += 64) {
        int row = rb + ro;            // row = tx*9 + dyi
        int tx  = row / PATCH;        // const divisor -> magic multiply
        int dyi = row - tx * PATCH;
        int y   = ty + dyi - MD;
        if ((unsigned)y < 64u) {
            float comp[4];
#pragma unroll
            for (int j = 0; j < 4; ++j) {
                int x  = q4 * 4 + j;
                int dx = x - tx;
                comp[j] = (dx >= -MD && dx <= MD) ? sVals[tx][dyi * PATCH + dx + MD] : 0.f;
            }
            out4[tx * 1024 + y * 16 + q4] = make_float4(comp[0], comp[1], comp[2], comp[3]);
        }
    }
}

extern "C" void kernel_launch(void* const* d_in, const int* in_sizes, int n_in,
                              void* d_out, int out_size, void* d_ws, size_t ws_size,
                              hipStream_t stream) {
    const float* f1 = (const float*)d_in[0];
    const float* f2 = (const float*)d_in[1];
    float* out = (float*)d_out;
    cv_kernel<<<NBAND + NZERO, BT, 0, stream>>>(f1, f2, out);
}

// Round 11
// 85.004 us; speedup vs baseline: 1.1734x; 1.1734x over previous
//
#include <hip/hip_runtime.h>

// Problem constants
#define MD 4
#define PATCH 9          // 2*MD+1
#define NBAND 256        // band-compute blocks: (b, ty) = 4 * 64
#define NZERO 1024       // zero-streaming blocks
#define BT 1024          // threads per block (16 waves)
// feat1/feat2: (4, 256, 64, 64) fp32
// out: (4, 4096, 64, 64) fp32 = 256 MB
//
// out[b, ty*64+tx, y, x] = sum_c f1[b,c,y,x] * f2[b,c,ty,tx]  if |ty-y|<=4 && |tx-x|<=4, else 0.
//
// Fused kernel, row-disjoint partition:
//   zero blocks: rows |y-ty|>4 (~220 MB predicated float4 stream)
//   band blocks: rows |y-ty|<=4 (~36 MB computed)
// Band block: stage ALL of f2[b,:,ty,:] into padded 72-wide LDS rows (margins = 0), ONE
// barrier, then 16 waves (cq = channel quarter, dyg -> dy rows {0,1}/{2,3}/{4,5}/{6,7,8})
// each do 64 channels x 2-3 dy rows: batched f1 loads + 9 consecutive ds_reads.
// sF2/sVals UNIONED (73.7 KB -> 2 blocks/CU, band+zero co-resident). Merge WITHOUT a
// zero-fill pass: cq==0 waves STORE their partials (exactly covering all read entries),
// barrier, cq 1-3 atomicAdd. No duplicate-row compute (R10's regression), no zero pass.

template<int ND>
__device__ __forceinline__ void band_core(
    const float* __restrict__ f1base,     // f1 + (b*256 + cq*64)*4096 + lane
    const float (* __restrict__ sF2)[72], // this wave's 64 padded channel rows
    int ty, int dy0, int lane,
    float acc[3][PATCH])
{
    int yoff[ND];                          // clamped; invalid rows discarded at merge
#pragma unroll
    for (int i = 0; i < ND; ++i) {
        int y = ty + dy0 + i - MD;
        y = y < 0 ? 0 : (y > 63 ? 63 : y);
        yoff[i] = y * 64;
    }

#pragma unroll 4
    for (int c = 0; c < 64; ++c) {
        const float* f1c = f1base + (size_t)c * 4096;
        float f1v[ND];
#pragma unroll
        for (int i = 0; i < ND; ++i)
            f1v[i] = f1c[yoff[i]];                    // batched coalesced global loads
        const float* wp = &sF2[c][lane];
        float sh[PATCH];
#pragma unroll
        for (int dxi = 0; dxi < PATCH; ++dxi)
            sh[dxi] = wp[8 - dxi];                    // f2[c,ty,lane-dxi+4]; margins give 0
#pragma unroll
        for (int i = 0; i < ND; ++i)
#pragma unroll
            for (int dxi = 0; dxi < PATCH; ++dxi)
                acc[i][dxi] = fmaf(f1v[i], sh[dxi], acc[i][dxi]);
    }
}

__global__ __launch_bounds__(BT, 8) void cv_kernel(
    const float* __restrict__ f1,
    const float* __restrict__ f2,
    float* __restrict__ out)
{
    const int tid = threadIdx.x;

    // ---------------- zero-streaming blocks ----------------
    if (blockIdx.x >= NBAND) {
        // float4 index i: bits [0:4)=x4, [4:10)=y, [10:16)=tx, [16:22)=ty, [22:24)=b
        float4* o4 = (float4*)out;
        const float4 z4 = make_float4(0.f, 0.f, 0.f, 0.f);
        const int total4 = 4 * 4096 * 64 * 16;            // 16,777,216
        const int stride = NZERO * BT;
        for (int i = (blockIdx.x - NBAND) * BT + tid; i < total4; i += stride) {
            int y  = (i >> 4) & 63;
            int ty = (i >> 16) & 63;
            int dy = y - ty;
            if (dy < -MD || dy > MD)
                o4[i] = z4;
        }
        return;
    }

    // ---------------- band-compute blocks ----------------
    const int bty = blockIdx.x;       // 0..255
    const int b   = bty >> 6;
    const int ty  = bty & 63;
    const int lane = tid & 63;        // u = x position
    const int w    = tid >> 6;        // 0..15
    const int cq   = w >> 2;          // channel quarter
    const int dyg  = w & 3;           // dy group: rows {0,1}/{2,3}/{4,5}/{6,7,8}
    const int dy0  = dyg * 2;
    const int nd   = (dyg == 3) ? 3 : 2;

    __shared__ float uLds[256 * 72];  // 73,728 B: sF2[256][72] during compute, sVals[64][81] after
    float (*sF2)[72] = (float(*)[72])uLds;

    // stage f2[b, c, ty, :] -> sF2[c][4..68), margins zeroed
    const float4* f2g = (const float4*)f2 + (size_t)(b * 256) * 1024 + ty * 16;
#pragma unroll
    for (int k = 0; k < 4; ++k) {
        int idx = k * BT + tid;       // 0..4095
        int cl = idx >> 4, x4 = idx & 15;
        *(float4*)&sF2[cl][4 + 4 * x4] = f2g[(size_t)cl * 1024 + x4];   // 16B-aligned
    }
    if (tid < 512) {
        int cl = tid >> 1, off = (tid & 1) ? 68 : 0;
        *(float4*)&sF2[cl][off] = make_float4(0.f, 0.f, 0.f, 0.f);
    }
    __syncthreads();

    float acc[3][PATCH];
#pragma unroll
    for (int i = 0; i < 3; ++i)
#pragma unroll
        for (int j = 0; j < PATCH; ++j) acc[i][j] = 0.f;

    const float* f1b = f1 + (size_t)(b * 256 + cq * 64) * 4096 + lane;
    const float (*sF2w)[72] = &sF2[cq * 64];

    if (dyg == 3) band_core<3>(f1b, sF2w, ty, dy0, lane, acc);
    else          band_core<2>(f1b, sF2w, ty, dy0, lane, acc);

    __syncthreads();                  // all sF2 reads complete; uLds becomes sVals
    float (*sVals)[81] = (float(*)[81])uLds;   // sVals[tx][dyi*9+dxi]

    // Merge without zero-fill: cq==0 waves cover every read entry exactly once -> store.
    if (cq == 0) {
#pragma unroll
        for (int i = 0; i < 3; ++i) {
            if (i >= nd) continue;    // wave-uniform
            int dyi = dy0 + i;
            int y = ty + dyi - MD;
            if ((unsigned)y >= 64u) continue;
#pragma unroll
            for (int dxi = 0; dxi < PATCH; ++dxi) {
                int tx = lane - (dxi - MD);
                if ((unsigned)tx < 64u)
                    sVals[tx][dyi * PATCH + dxi] = acc[i][dxi];   // stride 81: conflict-free
            }
        }
    }
    __syncthreads();
    if (cq != 0) {
#pragma unroll
        for (int i = 0; i < 3; ++i) {
            if (i >= nd) continue;
            int dyi = dy0 + i;
            int y = ty + dyi - MD;
            if ((unsigned)y >= 64u) continue;
#pragma unroll
            for (int dxi = 0; dxi < PATCH; ++dxi) {
                int tx = lane - (dxi - MD);
                if ((unsigned)tx < 64u)
                    atomicAdd(&sVals[tx][dyi * PATCH + dxi], acc[i][dxi]);
            }
        }
    }
    __syncthreads();

    // Band rows: full 64-float rows (9-wide value window, zeros elsewhere).
    float4* out4 = (float4*)(out + (size_t)(b * 4096 + ty * 64) * 4096);
    const int q4 = tid & 15;          // float4 index within a row
    const int ro = tid >> 4;          // 0..63
    for (int rb = 0; rb < 64 * PATCH; rb += 64) {
        int row = rb + ro;            // row = tx*9 + dyi
        int tx  = row / PATCH;        // const divisor -> magic multiply
        int dyi = row - tx * PATCH;
        int y   = ty + dyi - MD;
        if ((unsigned)y < 64u) {
            float comp[4];
#pragma unroll
            for (int j = 0; j < 4; ++j) {
                int x  = q4 * 4 + j;
                int dx = x - tx;
                comp[j] = (dx >= -MD && dx <= MD) ? sVals[tx][dyi * PATCH + dx + MD] : 0.f;
            }
            out4[tx * 1024 + y * 16 + q4] = make_float4(comp[0], comp[1], comp[2], comp[3]);
        }
    }
}

extern "C" void kernel_launch(void* const* d_in, const int* in_sizes, int n_in,
                              void* d_out, int out_size, void* d_ws, size_t ws_size,
                              hipStream_t stream) {
    const float* f1 = (const float*)d_in[0];
    const float* f2 = (const float*)d_in[1];
    float* out = (float*)d_out;
    cv_kernel<<<NBAND + NZERO, BT, 0, stream>>>(f1, f2, out);
}